// Round 7
// baseline (219.214 us; speedup 1.0000x reference)
//
#include <hip/hip_runtime.h>

// VQ via MFMA: x (32,64,64,64) fp32 NCHW, embed (512,64) fp32.
// bf16 hi/lo split (6 MFMA passes, fp32 acc) used for PRUNING only; every
// candidate within EPS of the row-min is re-checked in exact fp32 (same fmaf
// order as the R1-passing scalar kernel) -> argmin matches np (absmax 0 in R6).
//
// R7 (R6 was latency-bound: 85us vs ~15us issue floor, Occupancy 21%):
//  - per-wave ownership: wave w handles ALL 512 codes for rows w*16..w*16+15;
//    one __syncthreads total; queue/recheck/epilogue wave-local.
//  - double-buffered B-fragment prefetch (EH/EL/esq one tile ahead).
//  - LDS 40->22KB (A-frags converted from Xs32 in regs, no XsH/XsL staging).
//  - branchless packed-key min1/min2: key = (fenc(dist) & ~511) | n
//    (0.008 quantum << EPS; min-key tie -> smaller n, recheck decides exactly).

#define VQ_N 131072
#define VQ_D 64
#define VQ_K 512
#define VQ_HW 4096
#define ROWS 64          // rows per block (4 waves x 16 rows)
#define EPS 0.25f        // prune margin; approx-vs-exact |delta| <~ 1e-3
#define QW 256           // queue entries per wave
#define X32_STR 68       // floats/row, 16B-aligned, stride 4 banks

typedef __attribute__((ext_vector_type(8))) short short8;
typedef __attribute__((ext_vector_type(4))) float f32x4;

static __device__ __forceinline__ unsigned short f2bf(float f) {
    unsigned u = __float_as_uint(f);
    unsigned r = (u + 0x7fffu + ((u >> 16) & 1u)) >> 16;   // round-nearest-even
    return (unsigned short)r;
}
static __device__ __forceinline__ float bf2f(unsigned short h) {
    return __uint_as_float(((unsigned)h) << 16);
}
// order-preserving float<->uint (monotone, lossless; handles negatives)
static __device__ __forceinline__ unsigned fenc(float f) {
    unsigned u = __float_as_uint(f);
    return u ^ ((unsigned)(((int)u) >> 31) | 0x80000000u);
}
static __device__ __forceinline__ float fdec(unsigned k) {
    return (k & 0x80000000u) ? __uint_as_float(k ^ 0x80000000u)
                             : __uint_as_float(~k);
}

// prep: embed fp32 -> bf16 hi/lo (EH, EL); first 512 threads also do e_sq
__global__ __launch_bounds__(256) void vq_prep_kernel(
    const float* __restrict__ embed,
    unsigned short* __restrict__ EH, unsigned short* __restrict__ EL,
    float* __restrict__ esq) {
    int g = blockIdx.x * 256 + threadIdx.x;   // 32768 elems
    float f = embed[g];
    unsigned short h = f2bf(f);
    EH[g] = h;
    EL[g] = f2bf(f - bf2f(h));
    if (g < VQ_K) {
        const float* e = embed + g * VQ_D;
        float p0 = 0.f, p1 = 0.f, p2 = 0.f, p3 = 0.f;
#pragma unroll
        for (int d = 0; d < VQ_D; d += 4) {
            p0 = fmaf(e[d + 0], e[d + 0], p0);
            p1 = fmaf(e[d + 1], e[d + 1], p1);
            p2 = fmaf(e[d + 2], e[d + 2], p2);
            p3 = fmaf(e[d + 3], e[d + 3], p3);
        }
        esq[g] = (p0 + p1) + (p2 + p3);
    }
}

// load B fragments + esq for code-tile nt (16 codes) into the given regs
#define LOADB(nt, BH0, BH1, BL0, BL1, ES) {                        \
    int _eo = (((nt) << 4) + lrow) * VQ_D + (quad << 3);           \
    BH0 = *(const short8*)&EH[_eo];                                \
    BH1 = *(const short8*)&EH[_eo + 32];                           \
    BL0 = *(const short8*)&EL[_eo];                                \
    BL1 = *(const short8*)&EL[_eo + 32];                           \
    ES  = esq[((nt) << 4) + lrow]; }

// 6-MFMA hi/lo dist for tile nt + branchless min1/min2 key update
#define PROCESS(nt, BH0, BH1, BL0, BL1, ES) {                                  \
    f32x4 acc = {0.f, 0.f, 0.f, 0.f};                                          \
    acc = __builtin_amdgcn_mfma_f32_16x16x32_bf16(AH0, BH0, acc, 0, 0, 0);     \
    acc = __builtin_amdgcn_mfma_f32_16x16x32_bf16(AH1, BH1, acc, 0, 0, 0);     \
    acc = __builtin_amdgcn_mfma_f32_16x16x32_bf16(AH0, BL0, acc, 0, 0, 0);     \
    acc = __builtin_amdgcn_mfma_f32_16x16x32_bf16(AH1, BL1, acc, 0, 0, 0);     \
    acc = __builtin_amdgcn_mfma_f32_16x16x32_bf16(AL0, BH0, acc, 0, 0, 0);     \
    acc = __builtin_amdgcn_mfma_f32_16x16x32_bf16(AL1, BH1, acc, 0, 0, 0);     \
    unsigned _nn = ((nt) << 4) + lrow;                                         \
    _Pragma("unroll")                                                          \
    for (int i = 0; i < 4; ++i) {      /* C: col(n)=lane&15, row=quad*4+i */   \
        float v = fmaf(-2.f, acc[i], ES);                                      \
        unsigned key = (fenc(v) & 0xFFFFFE00u) | _nn;                          \
        unsigned hi = m1[i] > key ? m1[i] : key;                               \
        m1[i] = m1[i] < key ? m1[i] : key;                                     \
        m2[i] = m2[i] < hi  ? m2[i] : hi;                                      \
    } }

__global__ __launch_bounds__(256, 4) void vq_mfma_kernel(
    const float* __restrict__ x, const float* __restrict__ embed,
    const float* __restrict__ esq,
    const unsigned short* __restrict__ EH, const unsigned short* __restrict__ EL,
    float* __restrict__ out_q, float* __restrict__ out_idx) {
    __shared__ __align__(16) float Xs32[ROWS * X32_STR];   // 17408 B
    __shared__ unsigned long long row_best[ROWS];          // (fenc(exact)<<32)|n
    __shared__ int qcnt[4];
    __shared__ unsigned qbuf[4 * QW];

    const int t   = threadIdx.x;
    const int n0  = blockIdx.x * ROWS;
    const int b   = n0 >> 12;        // 64 | 4096 -> block stays in one image
    const int hw0 = n0 & 4095;

    if (t < ROWS) row_best[t] = ~0ull;
    if (t < 4) qcnt[t] = 0;

    // ---- stage X rows to LDS (fp32 only); global loads coalesced over hw ----
    {
        const int hw = t & 63;
        const int d0 = (t >> 6) * 16;
        const float* xb = x + (size_t)b * (VQ_D * VQ_HW) + hw0 + hw;
#pragma unroll
        for (int dd = 0; dd < 16; ++dd) {
            int d = d0 + dd;
            Xs32[hw * X32_STR + d] = xb[d * VQ_HW];
        }
    }
    __syncthreads();     // the ONLY block barrier

    const int lane = t & 63;
    const int wave = t >> 6;         // wave owns rows wave*16 .. wave*16+15
    const int lrow = lane & 15;
    const int quad = lane >> 4;

    // ---- A fragments from Xs32, converted in regs: A[m=lrow][k=quad*8+j] ----
    short8 AH0, AH1, AL0, AL1;
    {
        const float* xr = &Xs32[(wave * 16 + lrow) * X32_STR];
#pragma unroll
        for (int kk = 0; kk < 2; ++kk) {
            f32x4 a0 = *(const f32x4*)&xr[kk * 32 + quad * 8];
            f32x4 a1 = *(const f32x4*)&xr[kk * 32 + quad * 8 + 4];
            short8 h, l;
#pragma unroll
            for (int j = 0; j < 4; ++j) {
                unsigned short hh = f2bf(a0[j]);
                h[j] = (short)hh; l[j] = (short)f2bf(a0[j] - bf2f(hh));
                hh = f2bf(a1[j]);
                h[j + 4] = (short)hh; l[j + 4] = (short)f2bf(a1[j] - bf2f(hh));
            }
            if (kk == 0) { AH0 = h; AL0 = l; } else { AH1 = h; AL1 = l; }
        }
    }

    unsigned m1[4], m2[4];
#pragma unroll
    for (int i = 0; i < 4; ++i) { m1[i] = 0xFFFFFFFFu; m2[i] = 0xFFFFFFFFu; }

    // ---- main loop: 32 code-tiles, double-buffered B prefetch ----
    short8 bh0a, bh1a, bl0a, bl1a; float esa;
    short8 bh0b, bh1b, bl0b, bl1b; float esb;
    LOADB(0, bh0a, bh1a, bl0a, bl1a, esa)
#pragma unroll 1
    for (int nt = 0; nt < 32; nt += 2) {
        LOADB(nt + 1, bh0b, bh1b, bl0b, bl1b, esb)
        PROCESS(nt, bh0a, bh1a, bl0a, bl1a, esa)
        int ntp = (nt + 2 < 32) ? nt + 2 : 31;    // clamped harmless reload
        LOADB(ntp, bh0a, bh1a, bl0a, bl1a, esa)
        PROCESS(nt + 1, bh0b, bh1b, bl0b, bl1b, esb)
    }

    // ---- save per-lane locals, reduce min1 across the 16 n-lanes ----
    unsigned lm1[4], lm2[4], g1[4];
#pragma unroll
    for (int i = 0; i < 4; ++i) { lm1[i] = m1[i]; lm2[i] = m2[i]; g1[i] = m1[i]; }
#pragma unroll
    for (int s = 1; s <= 8; s <<= 1)
#pragma unroll
        for (int i = 0; i < 4; ++i) {
            unsigned o = __shfl_xor((int)g1[i], s);
            g1[i] = g1[i] < o ? g1[i] : o;
        }

    // ---- push candidates (within EPS of row-min) to this wave's queue ----
#pragma unroll
    for (int i = 0; i < 4; ++i) {
        int m = quad * 4 + i;                       // local row 0..15
        float thr = fdec(g1[i] & 0xFFFFFE00u) + EPS;
        if (fdec(lm1[i] & 0xFFFFFE00u) <= thr) {
            int id = atomicAdd(&qcnt[wave], 1);
            if (id < QW) qbuf[wave * QW + id] = ((unsigned)m << 9) | (lm1[i] & 511u);
        }
        if (fdec(lm2[i] & 0xFFFFFE00u) <= thr) {    // NaN-safe: unset -> false
            int id = atomicAdd(&qcnt[wave], 1);
            if (id < QW) qbuf[wave * QW + id] = ((unsigned)m << 9) | (lm2[i] & 511u);
        }
    }
    asm volatile("s_waitcnt lgkmcnt(0)");   // wave-local queue visible

    // ---- exact fp32 recheck (same fmaf order as R1 kernel), wave-local ----
    int qc = atomicAdd(&qcnt[wave], 0);
    if (qc > QW) qc = QW;
    for (int qi = lane; qi < qc; qi += 64) {
        unsigned e = qbuf[wave * QW + qi];
        int m = (int)(e >> 9), n = (int)(e & 511u);
        const float4* er = (const float4*)(embed + n * VQ_D);
        const float4* xr = (const float4*)&Xs32[(wave * 16 + m) * X32_STR];
        float dot = 0.f;
#pragma unroll
        for (int d4 = 0; d4 < 16; ++d4) {
            float4 ev = er[d4]; float4 xv = xr[d4];
            dot = fmaf(xv.x, ev.x, dot);
            dot = fmaf(xv.y, ev.y, dot);
            dot = fmaf(xv.z, ev.z, dot);
            dot = fmaf(xv.w, ev.w, dot);
        }
        float v = fmaf(-2.f, dot, esq[n]);
        unsigned long long key =
            (((unsigned long long)fenc(v)) << 32) | (unsigned)n;
        atomicMin(&row_best[wave * 16 + m], key);   // equal dist -> smaller n
    }
    asm volatile("s_waitcnt lgkmcnt(0)");   // row_best visible within wave

    // ---- outputs (wave-local, fully coalesced) ----
    if (lane < 16)
        out_idx[n0 + wave * 16 + lane] =
            (float)(unsigned)(row_best[wave * 16 + lane] & 0xffffffffu);

#pragma unroll
    for (int it = 0; it < 4; ++it) {
        int o   = it * 256 + lane * 4;              // 16 rows x 64 floats
        int row = o >> 6;
        int col = o & 63;
        unsigned k = (unsigned)(row_best[wave * 16 + row] & 0xffffffffu);
        float4 val = *(const float4*)(embed + k * VQ_D + col);
        *(float4*)(out_q + ((size_t)(n0 + wave * 16)) * VQ_D + o) = val;
    }
}

extern "C" void kernel_launch(void* const* d_in, const int* in_sizes, int n_in,
                              void* d_out, int out_size, void* d_ws, size_t ws_size,
                              hipStream_t stream) {
    const float* x     = (const float*)d_in[0];
    const float* embed = (const float*)d_in[1];
    float* out_q   = (float*)d_out;
    float* out_idx = (float*)d_out + (size_t)VQ_N * VQ_D;

    float* esq          = (float*)d_ws;                          // 512 f
    unsigned short* EH  = (unsigned short*)((char*)d_ws + 2048);
    unsigned short* EL  = (unsigned short*)((char*)d_ws + 2048 + VQ_K * VQ_D * 2);

    vq_prep_kernel<<<(VQ_K * VQ_D) / 256, 256, 0, stream>>>(embed, EH, EL, esq);
    vq_mfma_kernel<<<VQ_N / ROWS, 256, 0, stream>>>(x, embed, esq, EH, EL, out_q, out_idx);
}